// Round 1
// baseline (811.638 us; speedup 1.0000x reference)
//
#include <hip/hip_runtime.h>
#include <cstdint>
#include <cstddef>

#define T_TASKS 32
#define S_SHOT  2048
#define F_FEAT  1024
#define C_CLS   512
#define MARGIN  0.1f

typedef _Float16 f16;
typedef _Float16 f16x4 __attribute__((ext_vector_type(4)));
typedef _Float16 f16x8 __attribute__((ext_vector_type(8)));
typedef float    f32x4 __attribute__((ext_vector_type(4)));

// async global->LDS, 16B per lane; LDS dest is wave-uniform base + lane*16
__device__ __forceinline__ void gl_lds16(const void* g, void* l) {
  auto gp = (const __attribute__((address_space(1))) uint32_t*)(g);
  auto lp = (__attribute__((address_space(3))) uint32_t*)(l);
  __builtin_amdgcn_global_load_lds(gp, lp, 16, 0, 0);
}

__device__ __forceinline__ void upd3(float v, int i,
                                     float& v1, int& i1,
                                     float& v2, int& i2,
                                     float& v3, int& i3) {
  if (v > v1 || (v == v1 && i < i1)) { v3=v2; i3=i2; v2=v1; i2=i1; v1=v; i1=i; }
  else if (v > v2 || (v == v2 && i < i2)) { v3=v2; i3=i2; v2=v; i2=i; }
  else if (v > v3 || (v == v3 && i < i3)) { v3=v; i3=i; }
}

// ---------------------------------------------------------------------------
// Pre-pass: W fp32 -> Wh (f16 hi part) in k-tiled + bank-swizzled layout,
// and wsq[t,c] = 0.5*sum(w^2) (fp64-accurate, stored fp32 for the gate).
// Layout: for element (t,c,f): kt=f>>5, q=(f>>3)&3, j=f&7,
//   unit u = c*4 + ((q + (c>>1)) & 3)   (swizzle -> 2-way max LDS conflicts)
//   half index = ((t*32+kt)<<14) + u*8 + j
// ---------------------------------------------------------------------------
__global__ __launch_bounds__(256) void prep_w(const float* __restrict__ W,
                                              f16* __restrict__ Wh,
                                              float* __restrict__ wsq) {
  int rid = blockIdx.x * 4 + (threadIdx.x >> 6);  // (t,c) row, one wave each
  int ln  = threadIdx.x & 63;
  int c   = rid & (C_CLS - 1);
  int t   = rid >> 9;
  const float* wr = W + (size_t)rid * F_FEAT;
  double s = 0.0;
#pragma unroll
  for (int j = 0; j < 4; ++j) {
    int f = (j * 64 + ln) * 4;
    float4 v = *(const float4*)(wr + f);
    s += (double)v.x * v.x + (double)v.y * v.y +
         (double)v.z * v.z + (double)v.w * v.w;
    f16x4 h;
    h.x = (f16)v.x; h.y = (f16)v.y; h.z = (f16)v.z; h.w = (f16)v.w;
    int kt = f >> 5;
    int q  = (f >> 3) & 3;
    int jj = f & 7;                       // 0 or 4
    int u  = c * 4 + ((q + (c >> 1)) & 3);
    size_t off = ((size_t)(t * 32 + kt) << 14) + (size_t)u * 8 + jj;
    *(f16x4*)(Wh + off) = h;
  }
#pragma unroll
  for (int off = 32; off > 0; off >>= 1) s += __shfl_xor(s, off);
  if (ln == 0) wsq[rid] = (float)(0.5 * s);
}

// ---------------------------------------------------------------------------
// Main: per block = (task, 64 rows) x all 512 classes.
// 4 waves = 2 row-groups(32) x 2 col-groups(256).
// Score = (xh+xl)·wh - 0.5||w||^2 via 2 MFMA passes; fused argmax with
// fp64 refinement of rows whose top-2 gap < MARGIN.
// ---------------------------------------------------------------------------
__global__ __launch_bounds__(256, 2) void gemm_argmax(
    const float* __restrict__ X, const float* __restrict__ W,
    const f16* __restrict__ Wh, const float* __restrict__ wsq,
    int* __restrict__ out) {
  __shared__ __align__(16) f16 sWh[16384];       // 512c x 32k (swizzled units)
  __shared__ __align__(16) f16 sXh[64 * 40];     // 64r x 32k, stride 40 (pad)
  __shared__ __align__(16) f16 sXl[64 * 40];
  __shared__ float swsq[C_CLS];
  __shared__ float cv[64][2][3];
  __shared__ int   ci[64][2][3];
  __shared__ int   amb_cnt;
  __shared__ int   amb_list[64];

  const int tid = threadIdx.x;
  const int wv  = tid >> 6, ln = tid & 63;
  const int rg  = wv >> 1, cg = wv & 1;          // row-group, col-group
  const int m   = ln & 15, q = ln >> 4;
  const int bx  = blockIdx.x;
  const int t   = bx >> 5, rb = bx & 31;
  const int row0 = rb * 64;

  swsq[tid]       = wsq[t * C_CLS + tid];
  swsq[tid + 256] = wsq[t * C_CLS + tid + 256];
  if (tid == 0) amb_cnt = 0;

  const f32x4 zero4 = {0.f, 0.f, 0.f, 0.f};
  f32x4 acc[2][16];
#pragma unroll
  for (int a = 0; a < 2; ++a)
#pragma unroll
    for (int b = 0; b < 16; ++b) acc[a][b] = zero4;

  const float* Xblk = X + ((size_t)t * S_SHOT + row0) * F_FEAT;
  const f16*   Wht  = Wh + ((size_t)(t * 32) << 14);

  // per-lane fragment base addresses
  f16* aph = sXh + (rg * 32 + m) * 40 + q * 8;
  f16* apl = sXl + (rg * 32 + m) * 40 + q * 8;
  const int c0 = cg * 256 + m;
  const int u0 = c0 * 4 + ((q + (c0 >> 1)) & 3); // swizzle is ct-invariant
  const f16* bp = sWh + u0 * 8;

  for (int kt = 0; kt < 32; ++kt) {
    // stage W tile: 32KB, 8 x 1KB instructions per wave, direct-to-LDS
    const f16* gW = Wht + (kt << 14) + wv * 4096 + ln * 8;
    f16* lW = sWh + wv * 4096;
#pragma unroll
    for (int i = 0; i < 8; ++i) gl_lds16(gW + i * 512, lW + i * 512);

    // stage X tile with hi/lo split (2 x float4 per thread)
#pragma unroll
    for (int j = 0; j < 2; ++j) {
      int idx = tid + j * 256;
      int r = idx >> 3, q4 = idx & 7;
      float4 v = *(const float4*)(Xblk + (size_t)r * F_FEAT + kt * 32 + q4 * 4);
      f16x4 h, l;
      h.x = (f16)v.x; l.x = (f16)(v.x - (float)h.x);
      h.y = (f16)v.y; l.y = (f16)(v.y - (float)h.y);
      h.z = (f16)v.z; l.z = (f16)(v.z - (float)h.z);
      h.w = (f16)v.w; l.w = (f16)(v.w - (float)h.w);
      *(f16x4*)(sXh + r * 40 + q4 * 4) = h;
      *(f16x4*)(sXl + r * 40 + q4 * 4) = l;
    }
    __syncthreads();

    f16x8 ah0 = *(const f16x8*)(aph);
    f16x8 ah1 = *(const f16x8*)(aph + 16 * 40);
    f16x8 al0 = *(const f16x8*)(apl);
    f16x8 al1 = *(const f16x8*)(apl + 16 * 40);
#pragma unroll
    for (int ct = 0; ct < 16; ++ct) {
      f16x8 bh = *(const f16x8*)(bp + ct * 512);
      acc[0][ct] = __builtin_amdgcn_mfma_f32_16x16x32_f16(ah0, bh, acc[0][ct], 0, 0, 0);
      acc[0][ct] = __builtin_amdgcn_mfma_f32_16x16x32_f16(al0, bh, acc[0][ct], 0, 0, 0);
      acc[1][ct] = __builtin_amdgcn_mfma_f32_16x16x32_f16(ah1, bh, acc[1][ct], 0, 0, 0);
      acc[1][ct] = __builtin_amdgcn_mfma_f32_16x16x32_f16(al1, bh, acc[1][ct], 0, 0, 0);
    }
    __syncthreads();
  }

  // ---- epilogue: top-3 per (row, col-half); C/D layout: col=lane&15,
  // row = (lane>>4)*4 + reg
#pragma unroll
  for (int rt = 0; rt < 2; ++rt) {
#pragma unroll
    for (int rr = 0; rr < 4; ++rr) {
      float v1 = -3.4e38f, v2 = -3.4e38f, v3 = -3.4e38f;
      int   i1 = 0x7fffffff, i2 = 0x7fffffff, i3 = 0x7fffffff;
#pragma unroll
      for (int ct = 0; ct < 16; ++ct) {
        int cidx = c0 + ct * 16;
        float sc = acc[rt][ct][rr] - swsq[cidx];
        upd3(sc, cidx, v1, i1, v2, i2, v3, i3);
      }
      for (int off = 1; off < 16; off <<= 1) {
        float w1 = __shfl_xor(v1, off); int j1 = __shfl_xor(i1, off);
        float w2 = __shfl_xor(v2, off); int j2 = __shfl_xor(i2, off);
        float w3 = __shfl_xor(v3, off); int j3 = __shfl_xor(i3, off);
        upd3(w1, j1, v1, i1, v2, i2, v3, i3);
        upd3(w2, j2, v1, i1, v2, i2, v3, i3);
        upd3(w3, j3, v1, i1, v2, i2, v3, i3);
      }
      if (m == 0) {
        int row = rg * 32 + rt * 16 + q * 4 + rr;
        cv[row][cg][0] = v1; ci[row][cg][0] = i1;
        cv[row][cg][1] = v2; ci[row][cg][1] = i2;
        cv[row][cg][2] = v3; ci[row][cg][2] = i3;
      }
    }
  }
  __syncthreads();

  // ---- gate: write confident rows; queue ambiguous ones
  if (tid < 64) {
    float a1 = cv[tid][0][0]; int aj = ci[tid][0][0];
    float b1 = cv[tid][1][0]; int bj = ci[tid][1][0];
    float win, runner; int widx;
    if (a1 > b1 || (a1 == b1 && aj < bj)) {
      win = a1; widx = aj; runner = fmaxf(b1, cv[tid][0][1]);
    } else {
      win = b1; widx = bj; runner = fmaxf(a1, cv[tid][1][1]);
    }
    if (win - runner >= MARGIN) {
      out[t * S_SHOT + row0 + tid] = widx;
    } else {
      int p = atomicAdd(&amb_cnt, 1);
      amb_list[p] = tid;
    }
  }
  __syncthreads();

  // ---- fp64 refinement of ambiguous rows (expected ~0.5 per block)
  int nA = amb_cnt;
  for (int a = wv; a < nA; a += 4) {
    int rl = amb_list[a];
    const float* xr = X + ((size_t)t * S_SHOT + row0 + rl) * F_FEAT;
    double best = -1.0e300; int bidx = 0x7fffffff;
    for (int g = 0; g < 2; ++g) {
      for (int k = 0; k < 3; ++k) {
        int cidx = ci[rl][g][k];
        const float* wr = W + ((size_t)t * C_CLS + cidx) * F_FEAT;
        double sd = 0.0, sw = 0.0;
        for (int j = 0; j < 16; ++j) {
          float xv = xr[ln + 64 * j];
          float wv2 = wr[ln + 64 * j];
          sd += (double)xv * (double)wv2;
          sw += (double)wv2 * (double)wv2;
        }
#pragma unroll
        for (int off = 32; off > 0; off >>= 1) {
          sd += __shfl_xor(sd, off);
          sw += __shfl_xor(sw, off);
        }
        double sc = sd - 0.5 * sw;
        if (sc > best || (sc == best && cidx < bidx)) { best = sc; bidx = cidx; }
      }
    }
    if (ln == 0) out[t * S_SHOT + row0 + rl] = bidx;
  }
}

extern "C" void kernel_launch(void* const* d_in, const int* in_sizes, int n_in,
                              void* d_out, int out_size, void* d_ws, size_t ws_size,
                              hipStream_t stream) {
  (void)in_sizes; (void)n_in; (void)out_size;
  const float* X = (const float*)d_in[0];
  const float* W = (const float*)d_in[1];
  // temp (d_in[2]) is argmax-invariant; unused.
  const size_t wh_bytes = (size_t)T_TASKS * C_CLS * F_FEAT * sizeof(f16); // 33.5MB
  const size_t need = wh_bytes + (size_t)T_TASKS * C_CLS * sizeof(float);
  if (ws_size < need) return;  // fail loudly rather than corrupt memory
  f16*   Wh  = (f16*)d_ws;
  float* wsq = (float*)((char*)d_ws + wh_bytes);
  int*   out = (int*)d_out;
  prep_w<<<T_TASKS * C_CLS / 4, 256, 0, stream>>>(W, Wh, wsq);
  gemm_argmax<<<T_TASKS * (S_SHOT / 64), 256, 0, stream>>>(X, W, Wh, wsq, out);
}